// Round 1
// baseline (137.008 us; speedup 1.0000x reference)
//
#include <hip/hip_runtime.h>

// WaveletLoss: 3-level Haar DWT + soft-threshold + weighted mean-abs-diff.
// B=64, C=1, H=W=512.
// R8 = R7 with ONE change: __launch_bounds__(256,8) -> (256,4).
// Theory: the (256,8) bound caps VGPRs at 64, but the kernel's 16 up-front
// v4f stream loads alone need 64 VGPRs (plus addrs + cA1 arrays + accs),
// forcing spill-to-scratch or load serialization -- the ~3.4 TB/s "read
// wall". (256,4) gives a 128-VGPR budget: 4 blocks/CU = 16 waves/CU, each
// with 16 outstanding 1 KiB loads = 256 KB in flight/CU, far above the
// ~9 KB needed to cover HBM latency. Predicted: main ~40us -> ~25us.
// Non-temporal loads kept from R7 (proved neutral, single-variable A/B).

#define IMG_W 512
#define N_BATCH 64

#define THR1 (50.0f / 255.0f)
#define THR2 (25.0f / 255.0f)
#define THR3 (12.5f / 255.0f)

#define NBLK 2048   // 2048 blocks * 4 waves = 8192 tiles of 8x256

typedef float v4f __attribute__((ext_vector_type(4)));

__device__ __forceinline__ float softthr(float x, float thr) {
    float m = fmaxf(fabsf(x) - thr, 0.0f);
    return copysignf(m, x);
}

__device__ __forceinline__ float detail_term(float p, float t, float thr) {
    return fabsf(softthr(p, thr) - softthr(t, thr));
}

__device__ __forceinline__ void haar_quad(float a, float b, float c, float d,
                                          float& cA, float& cH, float& cV, float& cD) {
    cA = 0.5f * (a + b + c + d);
    cH = 0.5f * (a + b - c - d);
    cV = 0.5f * (a - b + c - d);
    cD = 0.5f * (a - b - c + d);
}

__device__ __forceinline__ v4f ld4nt(const float* p) {
    return __builtin_nontemporal_load((const v4f*)p);
}

__global__ __launch_bounds__(256, 4)
void wavelet_main(const float* __restrict__ pred,
                  const float* __restrict__ target,
                  float* __restrict__ ws) {
    constexpr float W1 = 1.0f / (1.0f * 3.0f * (float)(N_BATCH * 256 * 256));
    constexpr float W2 = 1.0f / (2.0f * 3.0f * (float)(N_BATCH * 128 * 128));
    constexpr float W3 = 1.0f / (3.0f * 3.0f * (float)(N_BATCH * 64 * 64));

    const int T  = blockIdx.x * 4 + (threadIdx.x >> 6);   // tile id 0..8191
    const int li = threadIdx.x & 63;

    const int img   = T >> 7;
    const int rem   = T & 127;
    const int half  = rem & 1;
    const int strip = rem >> 1;               // 8-row strip 0..63

    const size_t off = (size_t)img * (512 * 512)
                     + (size_t)strip * 8 * IMG_W
                     + half * 256 + 4 * li;
    const float* pb = pred + off;
    const float* tb = target + off;

    // all 16 stream loads issued up front, non-temporal
    v4f P0 = ld4nt(pb);                 v4f P1 = ld4nt(pb + IMG_W);
    v4f P2 = ld4nt(pb + 2 * IMG_W);     v4f P3 = ld4nt(pb + 3 * IMG_W);
    v4f P4 = ld4nt(pb + 4 * IMG_W);     v4f P5 = ld4nt(pb + 5 * IMG_W);
    v4f P6 = ld4nt(pb + 6 * IMG_W);     v4f P7 = ld4nt(pb + 7 * IMG_W);
    v4f Q0 = ld4nt(tb);                 v4f Q1 = ld4nt(tb + IMG_W);
    v4f Q2 = ld4nt(tb + 2 * IMG_W);     v4f Q3 = ld4nt(tb + 3 * IMG_W);
    v4f Q4 = ld4nt(tb + 4 * IMG_W);     v4f Q5 = ld4nt(tb + 5 * IMG_W);
    v4f Q6 = ld4nt(tb + 6 * IMG_W);     v4f Q7 = ld4nt(tb + 7 * IMG_W);

    float s1 = 0.0f, s2 = 0.0f;
    float cA1p[4][2], cA1t[4][2];

    // ---- level 1: row-pairs (2rp, 2rp+1), two quads per pair (in-lane) ----
    {
        float cA, cH, cV, cD, cAt, cHt, cVt, cDt;

        #define L1_PAIR(a, b, qa, qb, rp)                                              \
        {                                                                              \
            haar_quad((a).x, (a).y, (b).x, (b).y, cA, cH, cV, cD);                     \
            haar_quad((qa).x, (qa).y, (qb).x, (qb).y, cAt, cHt, cVt, cDt);             \
            s1 += detail_term(cH, cHt, THR1) + detail_term(cV, cVt, THR1)              \
                + detail_term(cD, cDt, THR1);                                          \
            cA1p[rp][0] = cA; cA1t[rp][0] = cAt;                                       \
            haar_quad((a).z, (a).w, (b).z, (b).w, cA, cH, cV, cD);                     \
            haar_quad((qa).z, (qa).w, (qb).z, (qb).w, cAt, cHt, cVt, cDt);             \
            s1 += detail_term(cH, cHt, THR1) + detail_term(cV, cVt, THR1)              \
                + detail_term(cD, cDt, THR1);                                          \
            cA1p[rp][1] = cA; cA1t[rp][1] = cAt;                                       \
        }

        L1_PAIR(P0, P1, Q0, Q1, 0)
        L1_PAIR(P2, P3, Q2, Q3, 1)
        L1_PAIR(P4, P5, Q4, Q5, 2)
        L1_PAIR(P6, P7, Q6, Q7, 3)
        #undef L1_PAIR
    }

    // ---- level 2: two quads fully in-lane ----
    float cA2p[2], cA2t[2];
    {
        float cH, cV, cD, cHt, cVt, cDt;
        haar_quad(cA1p[0][0], cA1p[0][1], cA1p[1][0], cA1p[1][1], cA2p[0], cH, cV, cD);
        haar_quad(cA1t[0][0], cA1t[0][1], cA1t[1][0], cA1t[1][1], cA2t[0], cHt, cVt, cDt);
        s2 += detail_term(cH, cHt, THR2) + detail_term(cV, cVt, THR2) + detail_term(cD, cDt, THR2);
        haar_quad(cA1p[2][0], cA1p[2][1], cA1p[3][0], cA1p[3][1], cA2p[1], cH, cV, cD);
        haar_quad(cA1t[2][0], cA1t[2][1], cA1t[3][0], cA1t[3][1], cA2t[1], cHt, cVt, cDt);
        s2 += detail_term(cH, cHt, THR2) + detail_term(cV, cVt, THR2) + detail_term(cD, cDt, THR2);
    }

    // ---- level 3: horizontal neighbor via shfl_xor(1), vertical in-lane ----
    float s3;
    {
        const float bP = __shfl_xor(cA2p[0], 1);
        const float dP = __shfl_xor(cA2p[1], 1);
        const float bT = __shfl_xor(cA2t[0], 1);
        const float dT = __shfl_xor(cA2t[1], 1);
        float cA, cH, cV, cD, cAt, cHt, cVt, cDt;
        haar_quad(cA2p[0], bP, cA2p[1], dP, cA, cH, cV, cD);
        haar_quad(cA2t[0], bT, cA2t[1], dT, cAt, cHt, cVt, cDt);
        s3 = detail_term(cH, cHt, THR3) + detail_term(cV, cVt, THR3) + detail_term(cD, cDt, THR3);
    }
    const float w3 = (li & 1) ? 0.0f : W3;

    float acc = W1 * s1 + W2 * s2 + w3 * s3;

    // wave reduction (64 lanes)
    #pragma unroll
    for (int off = 32; off > 0; off >>= 1)
        acc += __shfl_down(acc, off, 64);

    __shared__ float wave_sums[4];
    const int lane_b = threadIdx.x & 63;
    const int wave_b = threadIdx.x >> 6;
    if (lane_b == 0) wave_sums[wave_b] = acc;
    __syncthreads();
    if (threadIdx.x == 0)
        ws[blockIdx.x] = wave_sums[0] + wave_sums[1] + wave_sums[2] + wave_sums[3];
}

__global__ __launch_bounds__(256)
void wavelet_reduce(const float* __restrict__ ws, float* __restrict__ out) {
    const int tidx = threadIdx.x;
    float v = 0.0f;
    #pragma unroll
    for (int k = 0; k < NBLK / 256; ++k)
        v += ws[tidx + k * 256];

    #pragma unroll
    for (int off = 32; off > 0; off >>= 1)
        v += __shfl_down(v, off, 64);

    __shared__ float wave_sums[4];
    const int lane = tidx & 63;
    const int wave = tidx >> 6;
    if (lane == 0) wave_sums[wave] = v;
    __syncthreads();
    if (tidx == 0)
        out[0] = wave_sums[0] + wave_sums[1] + wave_sums[2] + wave_sums[3];
}

extern "C" void kernel_launch(void* const* d_in, const int* in_sizes, int n_in,
                              void* d_out, int out_size, void* d_ws, size_t ws_size,
                              hipStream_t stream) {
    const float* pred   = (const float*)d_in[0];
    const float* target = (const float*)d_in[1];
    float* out = (float*)d_out;
    float* ws  = (float*)d_ws;   // NBLK floats = 8 KB

    wavelet_main<<<NBLK, 256, 0, stream>>>(pred, target, ws);
    wavelet_reduce<<<1, 256, 0, stream>>>(ws, out);
}

// Round 2
// 135.422 us; speedup vs baseline: 1.0117x; 1.0117x over previous
//
#include <hip/hip_runtime.h>

// WaveletLoss: 3-level Haar DWT + soft-threshold + weighted mean-abs-diff.
// B=64, C=1, H=W=512.
// R9: persistent pipelined grid. R7 (nt) and R8 (launch-bounds) were both
// neutral -> per-wave MLP / L2 policy / VGPR budget are NOT the ~3.4 TB/s
// read wall. New theory: bursty load issue + 2-generation dispatch breaks
// the address co-arrival DRAM reads need (row-mates live 64 KiB apart =
// different blocks; they only row-hit if issued together; write-side fills
// re-batch in the DRAM write queue and hit 6.6 TB/s).
// Change: 1024 blocks (exactly 4/CU, single generation, all co-resident),
// 2 tiles per wave (T = wid, wid+4096 -> each round sweeps a contiguous
// half of memory), tile compute split into 4-row halves with next-tile
// loads software-pipelined between them so load issue is continuous.
// Tile geometry (8x256), nt loads, (256,4) bounds unchanged.

#define IMG_W 512
#define N_BATCH 64

#define THR1 (50.0f / 255.0f)
#define THR2 (25.0f / 255.0f)
#define THR3 (12.5f / 255.0f)

#define NBLK   1024   // 1024 blocks * 4 waves = 4096 waves, 2 tiles each
#define NWAVES 4096

typedef float v4f __attribute__((ext_vector_type(4)));

__device__ __forceinline__ float softthr(float x, float thr) {
    float m = fmaxf(fabsf(x) - thr, 0.0f);
    return copysignf(m, x);
}

__device__ __forceinline__ float detail_term(float p, float t, float thr) {
    return fabsf(softthr(p, thr) - softthr(t, thr));
}

__device__ __forceinline__ void haar_quad(float a, float b, float c, float d,
                                          float& cA, float& cH, float& cV, float& cD) {
    cA = 0.5f * (a + b + c + d);
    cH = 0.5f * (a + b - c - d);
    cV = 0.5f * (a - b + c - d);
    cD = 0.5f * (a - b - c + d);
}

__device__ __forceinline__ v4f ld4nt(const float* p) {
    return __builtin_nontemporal_load((const v4f*)p);
}

__device__ __forceinline__ size_t tile_offset(int T, int li) {
    const int img   = T >> 7;
    const int rem   = T & 127;
    const int half  = rem & 1;
    const int strip = rem >> 1;               // 8-row strip 0..63
    return (size_t)img * (512 * 512)
         + (size_t)strip * 8 * IMG_W
         + half * 256 + 4 * li;
}

// rows 0-3 of a tile: level-1 pairs 0,1 + level-2 quad 0
__device__ __forceinline__ void half_A(v4f P0, v4f P1, v4f P2, v4f P3,
                                       v4f Q0, v4f Q1, v4f Q2, v4f Q3,
                                       float& s1, float& s2,
                                       float& cA2p0, float& cA2t0) {
    float cA, cH, cV, cD, cAt, cHt, cVt, cDt;
    float p00, p01, p10, p11, t00, t01, t10, t11;

    haar_quad(P0.x, P0.y, P1.x, P1.y, cA, cH, cV, cD);
    haar_quad(Q0.x, Q0.y, Q1.x, Q1.y, cAt, cHt, cVt, cDt);
    s1 += detail_term(cH, cHt, THR1) + detail_term(cV, cVt, THR1) + detail_term(cD, cDt, THR1);
    p00 = cA; t00 = cAt;
    haar_quad(P0.z, P0.w, P1.z, P1.w, cA, cH, cV, cD);
    haar_quad(Q0.z, Q0.w, Q1.z, Q1.w, cAt, cHt, cVt, cDt);
    s1 += detail_term(cH, cHt, THR1) + detail_term(cV, cVt, THR1) + detail_term(cD, cDt, THR1);
    p01 = cA; t01 = cAt;

    haar_quad(P2.x, P2.y, P3.x, P3.y, cA, cH, cV, cD);
    haar_quad(Q2.x, Q2.y, Q3.x, Q3.y, cAt, cHt, cVt, cDt);
    s1 += detail_term(cH, cHt, THR1) + detail_term(cV, cVt, THR1) + detail_term(cD, cDt, THR1);
    p10 = cA; t10 = cAt;
    haar_quad(P2.z, P2.w, P3.z, P3.w, cA, cH, cV, cD);
    haar_quad(Q2.z, Q2.w, Q3.z, Q3.w, cAt, cHt, cVt, cDt);
    s1 += detail_term(cH, cHt, THR1) + detail_term(cV, cVt, THR1) + detail_term(cD, cDt, THR1);
    p11 = cA; t11 = cAt;

    haar_quad(p00, p01, p10, p11, cA2p0, cH, cV, cD);
    haar_quad(t00, t01, t10, t11, cA2t0, cHt, cVt, cDt);
    s2 += detail_term(cH, cHt, THR2) + detail_term(cV, cVt, THR2) + detail_term(cD, cDt, THR2);
}

// level 3 + weighting for one tile
__device__ __forceinline__ float tile_finish(float s1, float s2,
                                             float cA2p0, float cA2p1,
                                             float cA2t0, float cA2t1,
                                             float w3m) {
    constexpr float W1 = 1.0f / (1.0f * 3.0f * (float)(N_BATCH * 256 * 256));
    constexpr float W2 = 1.0f / (2.0f * 3.0f * (float)(N_BATCH * 128 * 128));
    constexpr float W3 = 1.0f / (3.0f * 3.0f * (float)(N_BATCH * 64 * 64));

    const float bP = __shfl_xor(cA2p0, 1);
    const float dP = __shfl_xor(cA2p1, 1);
    const float bT = __shfl_xor(cA2t0, 1);
    const float dT = __shfl_xor(cA2t1, 1);
    float cA, cH, cV, cD, cAt, cHt, cVt, cDt;
    haar_quad(cA2p0, bP, cA2p1, dP, cA, cH, cV, cD);
    haar_quad(cA2t0, bT, cA2t1, dT, cAt, cHt, cVt, cDt);
    const float s3 = detail_term(cH, cHt, THR3) + detail_term(cV, cVt, THR3)
                   + detail_term(cD, cDt, THR3);
    return W1 * s1 + W2 * s2 + (w3m * W3) * s3;
}

__global__ __launch_bounds__(256, 4)
void wavelet_main(const float* __restrict__ pred,
                  const float* __restrict__ target,
                  float* __restrict__ ws) {
    const int wid = blockIdx.x * 4 + (threadIdx.x >> 6);   // 0..4095
    const int li  = threadIdx.x & 63;

    const size_t off0 = tile_offset(wid, li);
    const size_t off1 = tile_offset(wid + NWAVES, li);
    const float* pb0 = pred + off0;
    const float* tb0 = target + off0;
    const float* pb1 = pred + off1;
    const float* tb1 = target + off1;

    const float w3m = (li & 1) ? 0.0f : 1.0f;
    float acc = 0.0f;

    // ---- tile 0: issue all 16 loads (two 4-row halves)
    v4f A0 = ld4nt(pb0);             v4f A1 = ld4nt(pb0 + IMG_W);
    v4f A2 = ld4nt(pb0 + 2 * IMG_W); v4f A3 = ld4nt(pb0 + 3 * IMG_W);
    v4f QA0 = ld4nt(tb0);             v4f QA1 = ld4nt(tb0 + IMG_W);
    v4f QA2 = ld4nt(tb0 + 2 * IMG_W); v4f QA3 = ld4nt(tb0 + 3 * IMG_W);
    v4f B0 = ld4nt(pb0 + 4 * IMG_W); v4f B1 = ld4nt(pb0 + 5 * IMG_W);
    v4f B2 = ld4nt(pb0 + 6 * IMG_W); v4f B3 = ld4nt(pb0 + 7 * IMG_W);
    v4f QB0 = ld4nt(tb0 + 4 * IMG_W); v4f QB1 = ld4nt(tb0 + 5 * IMG_W);
    v4f QB2 = ld4nt(tb0 + 6 * IMG_W); v4f QB3 = ld4nt(tb0 + 7 * IMG_W);

    float s1 = 0.0f, s2 = 0.0f;
    float cA2p0, cA2t0, cA2p1, cA2t1;

    // compute tile0 half A (waits only on the 8 A-loads)
    half_A(A0, A1, A2, A3, QA0, QA1, QA2, QA3, s1, s2, cA2p0, cA2t0);

    // prefetch tile1 half A into the now-dead A registers
    A0 = ld4nt(pb1);             A1 = ld4nt(pb1 + IMG_W);
    A2 = ld4nt(pb1 + 2 * IMG_W); A3 = ld4nt(pb1 + 3 * IMG_W);
    QA0 = ld4nt(tb1);             QA1 = ld4nt(tb1 + IMG_W);
    QA2 = ld4nt(tb1 + 2 * IMG_W); QA3 = ld4nt(tb1 + 3 * IMG_W);

    // compute tile0 half B (rows 4-7 -> level-1 pairs 2,3 + level-2 quad 1)
    half_A(B0, B1, B2, B3, QB0, QB1, QB2, QB3, s1, s2, cA2p1, cA2t1);

    acc += tile_finish(s1, s2, cA2p0, cA2p1, cA2t0, cA2t1, w3m);

    // prefetch tile1 half B
    B0 = ld4nt(pb1 + 4 * IMG_W); B1 = ld4nt(pb1 + 5 * IMG_W);
    B2 = ld4nt(pb1 + 6 * IMG_W); B3 = ld4nt(pb1 + 7 * IMG_W);
    QB0 = ld4nt(tb1 + 4 * IMG_W); QB1 = ld4nt(tb1 + 5 * IMG_W);
    QB2 = ld4nt(tb1 + 6 * IMG_W); QB3 = ld4nt(tb1 + 7 * IMG_W);

    // ---- tile 1
    s1 = 0.0f; s2 = 0.0f;
    half_A(A0, A1, A2, A3, QA0, QA1, QA2, QA3, s1, s2, cA2p0, cA2t0);
    half_A(B0, B1, B2, B3, QB0, QB1, QB2, QB3, s1, s2, cA2p1, cA2t1);
    acc += tile_finish(s1, s2, cA2p0, cA2p1, cA2t0, cA2t1, w3m);

    // wave reduction (64 lanes)
    #pragma unroll
    for (int off = 32; off > 0; off >>= 1)
        acc += __shfl_down(acc, off, 64);

    __shared__ float wave_sums[4];
    const int lane_b = threadIdx.x & 63;
    const int wave_b = threadIdx.x >> 6;
    if (lane_b == 0) wave_sums[wave_b] = acc;
    __syncthreads();
    if (threadIdx.x == 0)
        ws[blockIdx.x] = wave_sums[0] + wave_sums[1] + wave_sums[2] + wave_sums[3];
}

__global__ __launch_bounds__(256)
void wavelet_reduce(const float* __restrict__ ws, float* __restrict__ out) {
    const int tidx = threadIdx.x;
    float v = 0.0f;
    #pragma unroll
    for (int k = 0; k < NBLK / 256; ++k)
        v += ws[tidx + k * 256];

    #pragma unroll
    for (int off = 32; off > 0; off >>= 1)
        v += __shfl_down(v, off, 64);

    __shared__ float wave_sums[4];
    const int lane = tidx & 63;
    const int wave = tidx >> 6;
    if (lane == 0) wave_sums[wave] = v;
    __syncthreads();
    if (tidx == 0)
        out[0] = wave_sums[0] + wave_sums[1] + wave_sums[2] + wave_sums[3];
}

extern "C" void kernel_launch(void* const* d_in, const int* in_sizes, int n_in,
                              void* d_out, int out_size, void* d_ws, size_t ws_size,
                              hipStream_t stream) {
    const float* pred   = (const float*)d_in[0];
    const float* target = (const float*)d_in[1];
    float* out = (float*)d_out;
    float* ws  = (float*)d_ws;   // NBLK floats = 4 KB

    wavelet_main<<<NBLK, 256, 0, stream>>>(pred, target, ws);
    wavelet_reduce<<<1, 256, 0, stream>>>(ws, out);
}